// Round 5
// baseline (603.171 us; speedup 1.0000x reference)
//
#include <hip/hip_runtime.h>
#include <stdint.h>

// CasualSelfAttention (buggy reference preserved): B=4, S=4096, D=768, fp32 I/O
// (sniffed), bf16 MFMA internals.
// R12: revert the EXPSUM XCD supertile (single-variable). R10/R11 A/B proved
// the 4mx8n supertile itself costs +77us on EXPSUM (143->220us, WRITE +70MB)
// -- NOT the atomics (R11 removed them all, no change). With z=4 batches
// co-resident the per-XCD working set is ~4x the single-z model; revert to the
// R8-proven bijective 1D XCD chunk for ALL grids.
// Kept from R9-R11 (measured neutral-or-better, structurally cleaner):
//   - fused QKV (N=2304, v-segment transposed store via block-uniform trsw)
//   - fused sniff+normalize (one launch)
//   - atomic-free row-sums: EXPSUM writes f32 partials lsum2[16 cg][4096]
//     (dead Wq/Wk/Wv region); DIVL gathers 16 partials -> LDS reciprocals.
// gemm256 core: 256x256, 8 waves, BK=64, 8-phase, counted vmcnt, T2 swizzle,
// setprio (unchanged since R8; schedule proven not the limiter).
// Pipeline: normalize(+sniff) -> fused QKV proj (v transposed) ->
// per-group { P=exp(q@k^T) & partial rowsums; yT = vT@P^T / l } -> y'@Wc^T+bc.

typedef __bf16 bf16;
typedef __bf16 bf16x4 __attribute__((ext_vector_type(4)));
typedef __bf16 bf16x8 __attribute__((ext_vector_type(8)));
typedef float f32x4 __attribute__((ext_vector_type(4)));

#define OFF_Q    0L
#define OFF_K    25165824L
#define OFF_VT   50331648L
#define OFF_W    75497472L
#define OFF_B    80216064L
#define OFF_FLAG 80222208L
#define OFF_L    80223232L
#define OFF_ATT  80289792L
#define ATT_B    33554432L   // one batch of p, bytes
#define SD       3145728L    // 4096*768 elements
#define KOFF     12582912L   // (OFF_K-OFF_Q) in elems
#define VTOFF    25165824L   // (OFF_VT-OFF_Q) in elems

#define M_PLAIN  0   // C = (acc + bias[col]) * alpha, row-major packed (bf16/f32 via oflag)
#define M_EXPSUM 2   // C = bf16(exp(acc)); block-local partial row-sums -> lsum2[cg][row]
#define M_DIVL   3   // C = acc * (1 / sum_cg lsum2[cg][col])
#define M_QKV    4   // fused QKV: seg=n0/768 -> q(alpha)/k/vT2(transposed store)

__device__ __forceinline__ void glds16(const void* g, void* s) {
  __builtin_amdgcn_global_load_lds((const __attribute__((address_space(1))) void*)g,
                                   (__attribute__((address_space(3))) void*)s, 16, 0, 0);
}

#define SBAR()  do { asm volatile("" ::: "memory"); __builtin_amdgcn_s_barrier(); \
                     asm volatile("" ::: "memory"); } while (0)
#define LGKM0() do { asm volatile("s_waitcnt lgkmcnt(0)" ::: "memory"); \
                     __builtin_amdgcn_sched_barrier(0); } while (0)

// swapped order -> acc holds C^T fragment -> packed row-major stores
#define MFMA2(ac, aa, bb) do { \
  ac = __builtin_amdgcn_mfma_f32_16x16x32_bf16((bb)[0], (aa)[0], ac, 0, 0, 0); \
  ac = __builtin_amdgcn_mfma_f32_16x16x32_bf16((bb)[1], (aa)[1], ac, 0, 0, 0); \
} while (0)
// natural order -> packed transposed (column) stores
#define MFMA2T(ac, aa, bb) do { \
  ac = __builtin_amdgcn_mfma_f32_16x16x32_bf16((aa)[0], (bb)[0], ac, 0, 0, 0); \
  ac = __builtin_amdgcn_mfma_f32_16x16x32_bf16((aa)[1], (bb)[1], ac, 0, 0, 0); \
} while (0)

#define CLUSTER(I0, JO, AF) do { \
  if (trsw) { \
    _Pragma("unroll") for (int i = 0; i < 4; ++i) \
      _Pragma("unroll") for (int j = 0; j < 2; ++j) MFMA2T(acc[(I0)+i][(JO)+j], AF[i], bF[(JO)+j]); \
  } else { \
    _Pragma("unroll") for (int i = 0; i < 4; ++i) \
      _Pragma("unroll") for (int j = 0; j < 2; ++j) MFMA2(acc[(I0)+i][(JO)+j], AF[i], bF[(JO)+j]); \
  } \
} while (0)

__device__ __forceinline__ void norm8(const void* __restrict__ src, bf16* __restrict__ dst,
                                      long i, long n8, int f)
{
  if (i >= n8) return;
  bf16x8 o;
  if (f) {
    const float4 a = ((const float4*)src)[2 * i];
    const float4 b = ((const float4*)src)[2 * i + 1];
    o[0] = (bf16)a.x; o[1] = (bf16)a.y; o[2] = (bf16)a.z; o[3] = (bf16)a.w;
    o[4] = (bf16)b.x; o[5] = (bf16)b.y; o[6] = (bf16)b.z; o[7] = (bf16)b.w;
  } else {
    o = ((const bf16x8*)src)[i];
  }
  ((bf16x8*)dst)[i] = o;
}

// One launch: per-block dtype sniff (512 u16 of x, L2-broadcast), then
// x -> xn (6144 blocks), 4x W (288 each), 4x bias (1 each). No lsum zeroing.
__global__ void normalize_all(const void* x,
                              const void* w0, const void* b0, const void* w1, const void* b1,
                              const void* w2, const void* b2, const void* w3, const void* b3,
                              bf16* __restrict__ xn, bf16* __restrict__ Wn,
                              bf16* __restrict__ bn, int* __restrict__ flagOut)
{
  const int t = threadIdx.x;
  __shared__ int sflag;
  if (t == 0) sflag = 0;
  __syncthreads();
  {
    const uint16_t* xu = (const uint16_t*)x;
    const int e = (xu[2 * t] >> 7) & 0xFF;   // even u16: bf16 value / fp32 mantissa-low
    if (e >= 0xE0) sflag = 1;                // benign race, all writers store 1
  }
  __syncthreads();
  const int f = sflag;
  int b = blockIdx.x;
  if (b == 0 && t == 0) *flagOut = f;

  if (b < 6144) { norm8(x, xn, (long)b * 256 + t, 1572864L, f); return; }
  b -= 6144;
  if (b < 1152) {
    const int w = b / 288;
    const void* s = (w == 0) ? w0 : (w == 1) ? w1 : (w == 2) ? w2 : w3;
    norm8(s, Wn + (long)w * 589824L, (long)(b % 288) * 256 + t, 73728L, f);
    return;
  }
  b -= 1152;
  const void* s = (b == 0) ? b0 : (b == 1) ? b1 : (b == 2) ? b2 : b3;
  norm8(s, bn + (long)b * 768L, (long)t, 96L, f);
}

// C[m][n] = f(sum_k A[m][k]*Bm[n][k]); bf16 in, fp32 accum.
// 256x256 tile, 8 waves (2x4), BK=64, 8-phase schedule. K multiple of 64, >=128.
template <int MODE>
__launch_bounds__(512, 2)
__global__ void gemm256(const bf16* __restrict__ A, int lda, long strideA,
                        const bf16* __restrict__ Bm, int ldb, long strideB,
                        void* __restrict__ Cv, int ldc, long strideC,
                        int K, const bf16* __restrict__ bias, float alpha,
                        const int* __restrict__ oflag, float* __restrict__ lsum)
{
  __shared__ bf16 lds[65536];   // 2 bufs x 4 regions x 8192 elems = 128 KiB
  A  += (long)blockIdx.z * strideA;
  Bm += (long)blockIdx.z * strideB;
  // lsum = per-batch [16 colgrp][4096] f32 partial row-sums (no atomics).
  if (MODE == M_EXPSUM || MODE == M_DIVL) lsum += (long)blockIdx.z * 65536L;

  // XCD-aware bijective 1D chunk (R8-proven; supertile reverted in R12 after
  // R10/R11 A/B showed it costs +77us on EXPSUM). nwg%8==0 for all launches.
  const int gx = gridDim.x, gy = gridDim.y;
  const int lin = blockIdx.y * gx + blockIdx.x;
  const int cpx = (gx * gy) >> 3;
  const int nlin = (lin & 7) * cpx + (lin >> 3);
  const long m0 = (long)(nlin / gx) * 256, n0 = (long)(nlin % gx) * 256;

  // v-segment of fused QKV stores transposed -> natural MFMA operand order.
  const bool trsw = (MODE == M_QKV) && (n0 >= 1536);

  const int tid = threadIdx.x;
  const int wv = tid >> 6, lane = tid & 63;
  const int lr = lane & 15, quad = lane >> 4;
  const int wm = (wv >> 2) << 7;   // 0 / 128
  const int wn = (wv & 3) << 6;    // 0 / 64 / 128 / 192

  f32x4 acc[8][4];
  const f32x4 zero = {0.f, 0.f, 0.f, 0.f};
#pragma unroll
  for (int i = 0; i < 8; ++i)
#pragma unroll
    for (int j = 0; j < 4; ++j) acc[i][j] = zero;

  // --- staging: linear LDS dest (wave base + lane*16B), pre-swizzled global src.
  // Half-tile = 128 rows x 64 k (16 KiB); each wave issues 2 glds per half-tile.
  const int rowid = (wv << 4) + (lane >> 3);                // + 8 for 2nd glds
  const int colsw = ((lane & 7) ^ ((lane >> 3) & 7)) << 3;  // swizzled k-offset (elems)
  const long lda8 = 8L * lda, ldb8 = 8L * ldb;
  const bf16* paL = A + (m0 + rowid) * (long)lda + colsw;
  const bf16* paH = paL + 128L * lda;
  const bf16* pbL = Bm + (n0 + rowid) * (long)ldb + colsw;
  const bf16* pbH = pbL + 128L * ldb;

  auto STG = [&](const bf16* src, long ld8, int tbuf, int reg) {
    bf16* d = lds + (tbuf << 15) + (reg << 13) + (wv << 10);
    glds16(src, d);
    glds16(src + ld8, d + 512);
  };

  // region ids: R0=B-lo, R1=A-lo, R2=B-hi, R3=A-hi
  const int regA = 1 + ((wv >> 2) << 1);        // 1 or 3
  const int regB = wv & 2;                      // 0 or 2
  const int aoff = lr << 6;
  const int boff = ((wv & 1) << 12) + (lr << 6);
  const int xo  = (lr & 7) << 3;
  const int ok0 = (quad << 3) ^ xo;             // kk=0 swizzled read offset
  const int ok1 = (32 + (quad << 3)) ^ xo;      // kk=1

  const int nt = K >> 6;

  // prologue: tile0 R0-R3, tile1 R0-R2 (tile1.R3 staged at t=0 phase 1)
  STG(pbL, ldb8, 0, 0); STG(paL, lda8, 0, 1);
  STG(pbH, ldb8, 0, 2); STG(paH, lda8, 0, 3);
  asm volatile("s_waitcnt vmcnt(4)" ::: "memory");
  STG(pbL + 64, ldb8, 1, 0); STG(paL + 64, lda8, 1, 1);
  STG(pbH + 64, ldb8, 1, 2);
  asm volatile("s_waitcnt vmcnt(6)" ::: "memory");
  SBAR();

  for (int t = 0; t < nt; ++t) {
    const int buf = t & 1;
    const long k64 = (long)t << 6;
    const bf16* LA = lds + (buf << 15) + (regA << 13) + aoff;
    const bf16* LB = lds + (buf << 15) + (regB << 13) + boff;
    bf16x8 aL[4][2], aH[4][2], bF[4][2];

    // ---- phase 1: read aL (m0-3) + all B; stage (t+1).R3 (other buf) ----
#pragma unroll
    for (int i = 0; i < 4; ++i) {
      aL[i][0] = *(const bf16x8*)(LA + i * 1024 + ok0);
      aL[i][1] = *(const bf16x8*)(LA + i * 1024 + ok1);
    }
#pragma unroll
    for (int j = 0; j < 4; ++j) {
      bF[j][0] = *(const bf16x8*)(LB + j * 1024 + ok0);
      bF[j][1] = *(const bf16x8*)(LB + j * 1024 + ok1);
    }
    if (t + 1 < nt) STG(paH + k64 + 64, lda8, (t + 1) & 1, 3);
    SBAR();
    LGKM0();
    __builtin_amdgcn_s_setprio(1);
    CLUSTER(0, 0, aL);
    __builtin_amdgcn_s_setprio(0);
    SBAR();

    // ---- phase 2: read aH (m4-7); stage (t+2).R0 ----
#pragma unroll
    for (int i = 0; i < 4; ++i) {
      aH[i][0] = *(const bf16x8*)(LA + (4 + i) * 1024 + ok0);
      aH[i][1] = *(const bf16x8*)(LA + (4 + i) * 1024 + ok1);
    }
    if (t + 2 < nt) STG(pbL + k64 + 128, ldb8, buf, 0);
    SBAR();
    LGKM0();
    __builtin_amdgcn_s_setprio(1);
    CLUSTER(4, 0, aH);
    __builtin_amdgcn_s_setprio(0);
    SBAR();

    // ---- phase 3: stage (t+2).R1 ----
    if (t + 2 < nt) STG(paL + k64 + 128, lda8, buf, 1);
    SBAR();
    __builtin_amdgcn_s_setprio(1);
    CLUSTER(0, 2, aL);
    __builtin_amdgcn_s_setprio(0);
    SBAR();

    // ---- phase 4: stage (t+2).R2; counted vmcnt (drain only at tail) ----
    if (t + 2 < nt) STG(pbH + k64 + 128, ldb8, buf, 2);
    SBAR();
    __builtin_amdgcn_s_setprio(1);
    CLUSTER(4, 2, aH);
    __builtin_amdgcn_s_setprio(0);
    if (t + 2 < nt) asm volatile("s_waitcnt vmcnt(6)" ::: "memory");
    else            asm volatile("s_waitcnt vmcnt(0)" ::: "memory");
    SBAR();
  }

  if (MODE == M_QKV) {
    if (trsw) {
      // natural order: acc[i][j][r] = C[m0+wm+i*16+quad*4+r][n0+wn+j*16+lr].
      // store v^T into vT2 [768][16384]: vT2[col-1536][row].
      bf16* dst = (bf16*)Cv + VTOFF;
#pragma unroll
      for (int j = 0; j < 4; ++j) {
        const long col = n0 + wn + j * 16 + lr;
        const float bv = (float)bias[col];          // bias = bn concat, global col
#pragma unroll
        for (int i = 0; i < 8; ++i) {
          const long row = m0 + wm + i * 16 + quad * 4;
          bf16x4 v4;
#pragma unroll
          for (int r = 0; r < 4; ++r) v4[r] = (bf16)(acc[i][j][r] + bv);
          *(bf16x4*)(dst + (col - 1536L) * 16384L + row) = v4;
        }
      }
    } else {
      // swapped order: acc[i][j][r] = C[m0+wm+i*16+lr][n0+wn+j*16+quad*4+r].
      // seg 0 -> q (alpha), seg 1 -> k; row-major [16384][768].
      const int seg = (n0 >= 768);
      bf16* dst = (bf16*)Cv + (long)seg * KOFF;
      const float al = seg ? 1.f : alpha;
      long coll[4];
      f32x4 addv[4];
#pragma unroll
      for (int j = 0; j < 4; ++j) {
        const long coln = n0 + wn + j * 16 + quad * 4;
        const bf16x4 bb = *(const bf16x4*)(bias + coln);
#pragma unroll
        for (int r = 0; r < 4; ++r) addv[j][r] = (float)bb[r];
        coll[j] = coln - (long)seg * 768L;
      }
#pragma unroll
      for (int i = 0; i < 8; ++i) {
        const long row = m0 + wm + i * 16 + lr;
#pragma unroll
        for (int j = 0; j < 4; ++j) {
          bf16x4 v4;
#pragma unroll
          for (int r = 0; r < 4; ++r) v4[r] = (bf16)((acc[i][j][r] + addv[j][r]) * al);
          *(bf16x4*)(dst + row * 768L + coll[j]) = v4;
        }
      }
    }
    return;
  }

  // ---- shared epilogue for PLAIN / EXPSUM / DIVL ----
  // Swapped layout: acc[i][j][r] = C[m0+wm+i*16+lr][n0+wn+j*16+quad*4+r].
  float* fsh = (float*)lds;   // K-loop LDS is dead past the last barrier

  // DIVL: build reciprocal row-sums for this block's 256 cols once, in LDS.
  if (MODE == M_DIVL) {
    if (tid < 256) {
      float s = 0.f;
#pragma unroll
      for (int cg = 0; cg < 16; ++cg) s += lsum[cg * 4096 + n0 + tid];
      fsh[tid] = 1.0f / s;
    }
    __syncthreads();
  }

  const int outf32 = (MODE == M_PLAIN) && (oflag != nullptr) && (*oflag != 0);
  long colb[4];
  f32x4 addv[4];   // bias (M_PLAIN) or reciprocal row-sum (M_DIVL)
#pragma unroll
  for (int j = 0; j < 4; ++j) {
    colb[j] = n0 + wn + j * 16 + quad * 4;
    if (MODE == M_PLAIN) {
      const bf16x4 bb = *(const bf16x4*)(bias + colb[j]);
#pragma unroll
      for (int r = 0; r < 4; ++r) addv[j][r] = (float)bb[r];
    } else if (MODE == M_DIVL) {
      addv[j] = *(const f32x4*)(fsh + (int)(colb[j] - n0));
    }
  }
#pragma unroll
  for (int i = 0; i < 8; ++i) {
    const long row = m0 + wm + i * 16 + lr;
    char* rowp = (char*)Cv + ((long)blockIdx.z * strideC + row * (long)ldc) * (outf32 ? 4 : 2);
    float rsum = 0.f;
#pragma unroll
    for (int j = 0; j < 4; ++j) {
      f32x4 v;
#pragma unroll
      for (int r = 0; r < 4; ++r) {
        float t = acc[i][j][r];
        if (MODE == M_PLAIN)       t = (t + addv[j][r]) * alpha;
        else if (MODE == M_EXPSUM) t = __expf(t);
        else if (MODE == M_DIVL)   t = t * addv[j][r];
        v[r] = t;
      }
      if (MODE == M_PLAIN && outf32) {
        *(f32x4*)(rowp + colb[j] * 4) = v;
      } else {
        bf16x4 v4;
#pragma unroll
        for (int r = 0; r < 4; ++r) v4[r] = (bf16)v[r];
        if (MODE == M_EXPSUM) {
#pragma unroll
          for (int r = 0; r < 4; ++r) rsum += (float)v4[r];  // sum what PV reads
        }
        *(bf16x4*)(rowp + colb[j] * 2) = v4;
      }
    }
    if (MODE == M_EXPSUM) {
      // full 64-col strip sum for this row, per n-wave group -> LDS partial.
      rsum += __shfl_xor(rsum, 16);
      rsum += __shfl_xor(rsum, 32);
      if (quad == 0) fsh[((wm + i * 16 + lr) << 2) + (wv & 3)] = rsum;
    }
  }
  if (MODE == M_EXPSUM) {
    __syncthreads();
    if (tid < 256) {
      const f32x4 p = *(const f32x4*)(fsh + (tid << 2));
      lsum[(n0 >> 8) * 4096L + m0 + tid] = p[0] + p[1] + p[2] + p[3];
    }
  }
}

extern "C" void kernel_launch(void* const* d_in, const int* in_sizes, int n_in,
                              void* d_out, int out_size, void* d_ws, size_t ws_size,
                              hipStream_t stream)
{
  (void)in_sizes; (void)n_in; (void)out_size;
  char* ws = (char*)d_ws;

  if (ws_size < (size_t)(OFF_ATT + ATT_B)) return;  // out stays 0 -> 0.157 diagnostic
  const size_t avail = ws_size - (size_t)OFF_ATT;
  int group = (int)(avail / (size_t)ATT_B);
  group = group >= 4 ? 4 : (group >= 2 ? 2 : 1);

  bf16*  q    = (bf16*)(ws + OFF_Q);    // later: yT slots / y' flat
  bf16*  Wn   = (bf16*)(ws + OFF_W);    // 4 x 589824 (Wq,Wk,Wv contiguous = fused B)
  bf16*  bn   = (bf16*)(ws + OFF_B);    // 4 x 768 (bq,bk,bv contiguous = fused bias)
  int*   flg  = (int*)(ws + OFF_FLAG);
  bf16*  att  = (bf16*)(ws + OFF_ATT);
  bf16*  xn   = att;                    // alias: dead before att is written
  // lsum2 [4 batches][16 colgrp][4096] f32 = 1MB in the dead Wq/Wk/Wv region
  // (dead after the QKV dispatch; Wc at +3539KB is untouched).
  float* lsum2 = (float*)(ws + OFF_W);

  dim3 blk(256, 1, 1), blk2(512, 1, 1);
  const float qs = 0.03608439182435161f;  // 768^-0.5

  // 1) fused sniff + normalize (x, 4xW, 4xb): ONE launch, no lsum zeroing.
  normalize_all<<<7300, blk, 0, stream>>>(d_in[0],
                                          d_in[1], d_in[2], d_in[3], d_in[4],
                                          d_in[5], d_in[6], d_in[7], d_in[8],
                                          xn, Wn, bn, flg);

  // 2) fused QKV projection: M=16384, N=2304 (Wq|Wk|Wv), K=768.
  //    seg by n0: q (alpha=qs) / k / v->vT2 transposed store.
  dim3 gqkv(9, 64, 1);
  gemm256<M_QKV><<<gqkv, blk2, 0, stream>>>(xn, 768, 0, Wn, 768, 0,
                                            q, 768, 0, 768, bn, qs, nullptr, nullptr);

  // 3) Attention per group: P = exp(q@k^T) w/ partial row-sums; yT = vT@P^T / l.
  for (int g = 0; g < 4; g += group) {
    dim3 gs(16, 16, group);
    gemm256<M_EXPSUM><<<gs, blk2, 0, stream>>>(q + g * SD, 768, SD, q + KOFF + g * SD, 768, SD,
                                               att, 4096, 16777216L, 768, nullptr, 1.f,
                                               nullptr, lsum2 + g * 65536L);
    dim3 gpv(16, 3, group);
    gemm256<M_DIVL><<<gpv, blk2, 0, stream>>>(q + VTOFF + g * 4096L, 16384, 4096L,
                                              att, 4096, 16777216L,
                                              q + g * SD, 4096, SD, 4096, nullptr, 1.f,
                                              nullptr, lsum2 + g * 65536L);
  }

  // 4) out = y' @ Wc^T + bc  (q region flat == y' [16384][768]); fp32 out per flag.
  dim3 gout(3, 64, 1);
  gemm256<M_PLAIN><<<gout, blk2, 0, stream>>>(q, 768, 0, Wn + 3 * 589824L, 768, 0,
                                              d_out, 768, 0, 768, bn + 2304, 1.f, flg, nullptr);
}

// Round 6
// 482.483 us; speedup vs baseline: 1.2501x; 1.2501x over previous
//
#include <hip/hip_runtime.h>
#include <stdint.h>

// CasualSelfAttention (buggy reference preserved): B=4, S=4096, D=768, fp32 I/O
// (sniffed), bf16 MFMA internals.
// R13: un-fuse the QKV projection (single-variable vs R12). Exoneration matrix
// over R8/R10/R11/R12 pins the EXPSUM regression (143->220/227us) on the FUSED
// QKV dispatch: map (R12), atomics (R10vR11), and 256^2 projection tiles (R8
// used them, separate) are all exonerated. Post-fusion EXPSUM shows FETCH
// 111->72MB (q/k cache-resident) but WRITE 135->215MB (+80MB ~= dirty q/k/vT
// writebacks dragged through its window) at 1740->1290 GB/s effective.
// Restore R8's three separate projection launches (M_PLAIN q, M_PLAIN k,
// M_TRANSC vT). Kept (exonerated/neutral): fused sniff+normalize, atomic-free
// lsum2 row-sums, 1D XCD chunk, gemm256 8-phase core.
// Pipeline: normalize(+sniff) -> q/k/vT projections ->
// per-group { P=exp(q@k^T) & partial rowsums; yT = vT@P^T / l } -> y'@Wc^T+bc.

typedef __bf16 bf16;
typedef __bf16 bf16x4 __attribute__((ext_vector_type(4)));
typedef __bf16 bf16x8 __attribute__((ext_vector_type(8)));
typedef float f32x4 __attribute__((ext_vector_type(4)));

#define OFF_Q    0L
#define OFF_K    25165824L
#define OFF_VT   50331648L
#define OFF_W    75497472L
#define OFF_B    80216064L
#define OFF_FLAG 80222208L
#define OFF_L    80223232L
#define OFF_ATT  80289792L
#define ATT_B    33554432L   // one batch of p, bytes
#define SD       3145728L    // 4096*768 elements
#define KOFF     12582912L   // (OFF_K-OFF_Q) in elems
#define VTOFF    25165824L   // (OFF_VT-OFF_Q) in elems

#define M_PLAIN  0   // C = (acc + bias[col]) * alpha, row-major packed (bf16/f32 via oflag)
#define M_TRANSC 1   // C^T store, packed column bf16x4 (natural operand order)
#define M_EXPSUM 2   // C = bf16(exp(acc)); block-local partial row-sums -> lsum2[cg][row]
#define M_DIVL   3   // C = acc * (1 / sum_cg lsum2[cg][col])

__device__ __forceinline__ void glds16(const void* g, void* s) {
  __builtin_amdgcn_global_load_lds((const __attribute__((address_space(1))) void*)g,
                                   (__attribute__((address_space(3))) void*)s, 16, 0, 0);
}

#define SBAR()  do { asm volatile("" ::: "memory"); __builtin_amdgcn_s_barrier(); \
                     asm volatile("" ::: "memory"); } while (0)
#define LGKM0() do { asm volatile("s_waitcnt lgkmcnt(0)" ::: "memory"); \
                     __builtin_amdgcn_sched_barrier(0); } while (0)

// swapped order -> acc holds C^T fragment -> packed row-major stores
#define MFMA2(ac, aa, bb) do { \
  ac = __builtin_amdgcn_mfma_f32_16x16x32_bf16((bb)[0], (aa)[0], ac, 0, 0, 0); \
  ac = __builtin_amdgcn_mfma_f32_16x16x32_bf16((bb)[1], (aa)[1], ac, 0, 0, 0); \
} while (0)
// natural order -> packed transposed (column) stores
#define MFMA2T(ac, aa, bb) do { \
  ac = __builtin_amdgcn_mfma_f32_16x16x32_bf16((aa)[0], (bb)[0], ac, 0, 0, 0); \
  ac = __builtin_amdgcn_mfma_f32_16x16x32_bf16((aa)[1], (bb)[1], ac, 0, 0, 0); \
} while (0)

// MODE is a template constant -> branch folds at compile time.
#define CLUSTER(I0, JO, AF) do { \
  if (MODE == M_TRANSC) { \
    _Pragma("unroll") for (int i = 0; i < 4; ++i) \
      _Pragma("unroll") for (int j = 0; j < 2; ++j) MFMA2T(acc[(I0)+i][(JO)+j], AF[i], bF[(JO)+j]); \
  } else { \
    _Pragma("unroll") for (int i = 0; i < 4; ++i) \
      _Pragma("unroll") for (int j = 0; j < 2; ++j) MFMA2(acc[(I0)+i][(JO)+j], AF[i], bF[(JO)+j]); \
  } \
} while (0)

__device__ __forceinline__ void norm8(const void* __restrict__ src, bf16* __restrict__ dst,
                                      long i, long n8, int f)
{
  if (i >= n8) return;
  bf16x8 o;
  if (f) {
    const float4 a = ((const float4*)src)[2 * i];
    const float4 b = ((const float4*)src)[2 * i + 1];
    o[0] = (bf16)a.x; o[1] = (bf16)a.y; o[2] = (bf16)a.z; o[3] = (bf16)a.w;
    o[4] = (bf16)b.x; o[5] = (bf16)b.y; o[6] = (bf16)b.z; o[7] = (bf16)b.w;
  } else {
    o = ((const bf16x8*)src)[i];
  }
  ((bf16x8*)dst)[i] = o;
}

// One launch: per-block dtype sniff (512 u16 of x, L2-broadcast), then
// x -> xn (6144 blocks), 4x W (288 each), 4x bias (1 each). No lsum zeroing.
__global__ void normalize_all(const void* x,
                              const void* w0, const void* b0, const void* w1, const void* b1,
                              const void* w2, const void* b2, const void* w3, const void* b3,
                              bf16* __restrict__ xn, bf16* __restrict__ Wn,
                              bf16* __restrict__ bn, int* __restrict__ flagOut)
{
  const int t = threadIdx.x;
  __shared__ int sflag;
  if (t == 0) sflag = 0;
  __syncthreads();
  {
    const uint16_t* xu = (const uint16_t*)x;
    const int e = (xu[2 * t] >> 7) & 0xFF;   // even u16: bf16 value / fp32 mantissa-low
    if (e >= 0xE0) sflag = 1;                // benign race, all writers store 1
  }
  __syncthreads();
  const int f = sflag;
  int b = blockIdx.x;
  if (b == 0 && t == 0) *flagOut = f;

  if (b < 6144) { norm8(x, xn, (long)b * 256 + t, 1572864L, f); return; }
  b -= 6144;
  if (b < 1152) {
    const int w = b / 288;
    const void* s = (w == 0) ? w0 : (w == 1) ? w1 : (w == 2) ? w2 : w3;
    norm8(s, Wn + (long)w * 589824L, (long)(b % 288) * 256 + t, 73728L, f);
    return;
  }
  b -= 1152;
  const void* s = (b == 0) ? b0 : (b == 1) ? b1 : (b == 2) ? b2 : b3;
  norm8(s, bn + (long)b * 768L, (long)t, 96L, f);
}

// C[m][n] = f(sum_k A[m][k]*Bm[n][k]); bf16 in, fp32 accum.
// 256x256 tile, 8 waves (2x4), BK=64, 8-phase schedule. K multiple of 64, >=128.
template <int MODE>
__launch_bounds__(512, 2)
__global__ void gemm256(const bf16* __restrict__ A, int lda, long strideA,
                        const bf16* __restrict__ Bm, int ldb, long strideB,
                        void* __restrict__ Cv, int ldc, long strideC,
                        int K, const bf16* __restrict__ bias, float alpha,
                        const int* __restrict__ oflag, float* __restrict__ lsum)
{
  __shared__ bf16 lds[65536];   // 2 bufs x 4 regions x 8192 elems = 128 KiB
  A  += (long)blockIdx.z * strideA;
  Bm += (long)blockIdx.z * strideB;
  // lsum = per-batch [16 colgrp][4096] f32 partial row-sums (no atomics).
  if (MODE == M_EXPSUM || MODE == M_DIVL) lsum += (long)blockIdx.z * 65536L;

  // XCD-aware bijective 1D chunk (R8-proven). nwg%8==0 for all launches.
  const int gx = gridDim.x, gy = gridDim.y;
  const int lin = blockIdx.y * gx + blockIdx.x;
  const int cpx = (gx * gy) >> 3;
  const int nlin = (lin & 7) * cpx + (lin >> 3);
  const long m0 = (long)(nlin / gx) * 256, n0 = (long)(nlin % gx) * 256;

  const int tid = threadIdx.x;
  const int wv = tid >> 6, lane = tid & 63;
  const int lr = lane & 15, quad = lane >> 4;
  const int wm = (wv >> 2) << 7;   // 0 / 128
  const int wn = (wv & 3) << 6;    // 0 / 64 / 128 / 192

  f32x4 acc[8][4];
  const f32x4 zero = {0.f, 0.f, 0.f, 0.f};
#pragma unroll
  for (int i = 0; i < 8; ++i)
#pragma unroll
    for (int j = 0; j < 4; ++j) acc[i][j] = zero;

  // --- staging: linear LDS dest (wave base + lane*16B), pre-swizzled global src.
  // Half-tile = 128 rows x 64 k (16 KiB); each wave issues 2 glds per half-tile.
  const int rowid = (wv << 4) + (lane >> 3);                // + 8 for 2nd glds
  const int colsw = ((lane & 7) ^ ((lane >> 3) & 7)) << 3;  // swizzled k-offset (elems)
  const long lda8 = 8L * lda, ldb8 = 8L * ldb;
  const bf16* paL = A + (m0 + rowid) * (long)lda + colsw;
  const bf16* paH = paL + 128L * lda;
  const bf16* pbL = Bm + (n0 + rowid) * (long)ldb + colsw;
  const bf16* pbH = pbL + 128L * ldb;

  auto STG = [&](const bf16* src, long ld8, int tbuf, int reg) {
    bf16* d = lds + (tbuf << 15) + (reg << 13) + (wv << 10);
    glds16(src, d);
    glds16(src + ld8, d + 512);
  };

  // region ids: R0=B-lo, R1=A-lo, R2=B-hi, R3=A-hi
  const int regA = 1 + ((wv >> 2) << 1);        // 1 or 3
  const int regB = wv & 2;                      // 0 or 2
  const int aoff = lr << 6;
  const int boff = ((wv & 1) << 12) + (lr << 6);
  const int xo  = (lr & 7) << 3;
  const int ok0 = (quad << 3) ^ xo;             // kk=0 swizzled read offset
  const int ok1 = (32 + (quad << 3)) ^ xo;      // kk=1

  const int nt = K >> 6;

  // prologue: tile0 R0-R3, tile1 R0-R2 (tile1.R3 staged at t=0 phase 1)
  STG(pbL, ldb8, 0, 0); STG(paL, lda8, 0, 1);
  STG(pbH, ldb8, 0, 2); STG(paH, lda8, 0, 3);
  asm volatile("s_waitcnt vmcnt(4)" ::: "memory");
  STG(pbL + 64, ldb8, 1, 0); STG(paL + 64, lda8, 1, 1);
  STG(pbH + 64, ldb8, 1, 2);
  asm volatile("s_waitcnt vmcnt(6)" ::: "memory");
  SBAR();

  for (int t = 0; t < nt; ++t) {
    const int buf = t & 1;
    const long k64 = (long)t << 6;
    const bf16* LA = lds + (buf << 15) + (regA << 13) + aoff;
    const bf16* LB = lds + (buf << 15) + (regB << 13) + boff;
    bf16x8 aL[4][2], aH[4][2], bF[4][2];

    // ---- phase 1: read aL (m0-3) + all B; stage (t+1).R3 (other buf) ----
#pragma unroll
    for (int i = 0; i < 4; ++i) {
      aL[i][0] = *(const bf16x8*)(LA + i * 1024 + ok0);
      aL[i][1] = *(const bf16x8*)(LA + i * 1024 + ok1);
    }
#pragma unroll
    for (int j = 0; j < 4; ++j) {
      bF[j][0] = *(const bf16x8*)(LB + j * 1024 + ok0);
      bF[j][1] = *(const bf16x8*)(LB + j * 1024 + ok1);
    }
    if (t + 1 < nt) STG(paH + k64 + 64, lda8, (t + 1) & 1, 3);
    SBAR();
    LGKM0();
    __builtin_amdgcn_s_setprio(1);
    CLUSTER(0, 0, aL);
    __builtin_amdgcn_s_setprio(0);
    SBAR();

    // ---- phase 2: read aH (m4-7); stage (t+2).R0 ----
#pragma unroll
    for (int i = 0; i < 4; ++i) {
      aH[i][0] = *(const bf16x8*)(LA + (4 + i) * 1024 + ok0);
      aH[i][1] = *(const bf16x8*)(LA + (4 + i) * 1024 + ok1);
    }
    if (t + 2 < nt) STG(pbL + k64 + 128, ldb8, buf, 0);
    SBAR();
    LGKM0();
    __builtin_amdgcn_s_setprio(1);
    CLUSTER(4, 0, aH);
    __builtin_amdgcn_s_setprio(0);
    SBAR();

    // ---- phase 3: stage (t+2).R1 ----
    if (t + 2 < nt) STG(paL + k64 + 128, lda8, buf, 1);
    SBAR();
    __builtin_amdgcn_s_setprio(1);
    CLUSTER(0, 2, aL);
    __builtin_amdgcn_s_setprio(0);
    SBAR();

    // ---- phase 4: stage (t+2).R2; counted vmcnt (drain only at tail) ----
    if (t + 2 < nt) STG(pbH + k64 + 128, ldb8, buf, 2);
    SBAR();
    __builtin_amdgcn_s_setprio(1);
    CLUSTER(4, 2, aH);
    __builtin_amdgcn_s_setprio(0);
    if (t + 2 < nt) asm volatile("s_waitcnt vmcnt(6)" ::: "memory");
    else            asm volatile("s_waitcnt vmcnt(0)" ::: "memory");
    SBAR();
  }

  if (MODE == M_TRANSC) {
    // natural order: acc[i][j][r] = C[m0+wm+i*16+quad*4+r][n0+wn+j*16+lr].
    // store C^T packed: Cv[col][row], ldc = C^T leading dim.
#pragma unroll
    for (int j = 0; j < 4; ++j) {
      const long col = n0 + wn + j * 16 + lr;
      const float bv = (float)bias[col];
#pragma unroll
      for (int i = 0; i < 8; ++i) {
        const long row = m0 + wm + i * 16 + quad * 4;
        bf16x4 v4;
#pragma unroll
        for (int r = 0; r < 4; ++r) v4[r] = (bf16)((acc[i][j][r] + bv) * alpha);
        *(bf16x4*)((bf16*)Cv + (long)blockIdx.z * strideC + col * (long)ldc + row) = v4;
      }
    }
    return;
  }

  // ---- shared epilogue for PLAIN / EXPSUM / DIVL ----
  // Swapped layout: acc[i][j][r] = C[m0+wm+i*16+lr][n0+wn+j*16+quad*4+r].
  float* fsh = (float*)lds;   // K-loop LDS is dead past the last barrier

  // DIVL: build reciprocal row-sums for this block's 256 cols once, in LDS.
  if (MODE == M_DIVL) {
    if (tid < 256) {
      float s = 0.f;
#pragma unroll
      for (int cg = 0; cg < 16; ++cg) s += lsum[cg * 4096 + n0 + tid];
      fsh[tid] = 1.0f / s;
    }
    __syncthreads();
  }

  const int outf32 = (MODE == M_PLAIN) && (oflag != nullptr) && (*oflag != 0);
  long colb[4];
  f32x4 addv[4];   // bias (M_PLAIN) or reciprocal row-sum (M_DIVL)
#pragma unroll
  for (int j = 0; j < 4; ++j) {
    colb[j] = n0 + wn + j * 16 + quad * 4;
    if (MODE == M_PLAIN) {
      const bf16x4 bb = *(const bf16x4*)(bias + colb[j]);
#pragma unroll
      for (int r = 0; r < 4; ++r) addv[j][r] = (float)bb[r];
    } else if (MODE == M_DIVL) {
      addv[j] = *(const f32x4*)(fsh + (int)(colb[j] - n0));
    }
  }
#pragma unroll
  for (int i = 0; i < 8; ++i) {
    const long row = m0 + wm + i * 16 + lr;
    char* rowp = (char*)Cv + ((long)blockIdx.z * strideC + row * (long)ldc) * (outf32 ? 4 : 2);
    float rsum = 0.f;
#pragma unroll
    for (int j = 0; j < 4; ++j) {
      f32x4 v;
#pragma unroll
      for (int r = 0; r < 4; ++r) {
        float t = acc[i][j][r];
        if (MODE == M_PLAIN)       t = (t + addv[j][r]) * alpha;
        else if (MODE == M_EXPSUM) t = __expf(t);
        else if (MODE == M_DIVL)   t = t * addv[j][r];
        v[r] = t;
      }
      if (MODE == M_PLAIN && outf32) {
        *(f32x4*)(rowp + colb[j] * 4) = v;
      } else {
        bf16x4 v4;
#pragma unroll
        for (int r = 0; r < 4; ++r) v4[r] = (bf16)v[r];
        if (MODE == M_EXPSUM) {
#pragma unroll
          for (int r = 0; r < 4; ++r) rsum += (float)v4[r];  // sum what PV reads
        }
        *(bf16x4*)(rowp + colb[j] * 2) = v4;
      }
    }
    if (MODE == M_EXPSUM) {
      // full 64-col strip sum for this row, per n-wave group -> LDS partial.
      rsum += __shfl_xor(rsum, 16);
      rsum += __shfl_xor(rsum, 32);
      if (quad == 0) fsh[((wm + i * 16 + lr) << 2) + (wv & 3)] = rsum;
    }
  }
  if (MODE == M_EXPSUM) {
    __syncthreads();
    if (tid < 256) {
      const f32x4 p = *(const f32x4*)(fsh + (tid << 2));
      lsum[(n0 >> 8) * 4096L + m0 + tid] = p[0] + p[1] + p[2] + p[3];
    }
  }
}

extern "C" void kernel_launch(void* const* d_in, const int* in_sizes, int n_in,
                              void* d_out, int out_size, void* d_ws, size_t ws_size,
                              hipStream_t stream)
{
  (void)in_sizes; (void)n_in; (void)out_size;
  char* ws = (char*)d_ws;

  if (ws_size < (size_t)(OFF_ATT + ATT_B)) return;  // out stays 0 -> 0.157 diagnostic
  const size_t avail = ws_size - (size_t)OFF_ATT;
  int group = (int)(avail / (size_t)ATT_B);
  group = group >= 4 ? 4 : (group >= 2 ? 2 : 1);

  bf16*  q    = (bf16*)(ws + OFF_Q);    // later: yT slots / y' flat
  bf16*  k    = (bf16*)(ws + OFF_K);
  bf16*  vT2  = (bf16*)(ws + OFF_VT);   // [768][16384]
  bf16*  Wn   = (bf16*)(ws + OFF_W);    // 4 x 589824
  bf16*  bn   = (bf16*)(ws + OFF_B);    // 4 x 768
  int*   flg  = (int*)(ws + OFF_FLAG);
  bf16*  att  = (bf16*)(ws + OFF_ATT);
  bf16*  xn   = att;                    // alias: dead before att is written
  // lsum2 [4 batches][16 colgrp][4096] f32 = 1MB in the dead Wq region
  // (dead after the projections; < Wq's 1.15MB, Wk/Wv/Wc untouched).
  float* lsum2 = (float*)(ws + OFF_W);

  dim3 blk(256, 1, 1), blk2(512, 1, 1);
  const float qs = 0.03608439182435161f;  // 768^-0.5

  // 1) fused sniff + normalize (x, 4xW, 4xb): ONE launch.
  normalize_all<<<7300, blk, 0, stream>>>(d_in[0],
                                          d_in[1], d_in[2], d_in[3], d_in[4],
                                          d_in[5], d_in[6], d_in[7], d_in[8],
                                          xn, Wn, bn, flg);

  // 2) QKV projections, SEPARATE launches (R8-proven): M=16384, N=768, K=768.
  //    v stored transposed into vT2.
  dim3 gproj(3, 64, 1);
  gemm256<M_PLAIN><<<gproj, blk2, 0, stream>>>(xn, 768, 0, Wn + 0 * 589824L, 768, 0,
                                               q, 768, 0, 768, bn + 0, qs, nullptr, nullptr);
  gemm256<M_PLAIN><<<gproj, blk2, 0, stream>>>(xn, 768, 0, Wn + 1 * 589824L, 768, 0,
                                               k, 768, 0, 768, bn + 768, 1.f, nullptr, nullptr);
  gemm256<M_TRANSC><<<gproj, blk2, 0, stream>>>(xn, 768, 0, Wn + 2 * 589824L, 768, 0,
                                                vT2, 16384, 0, 768, bn + 1536, 1.f, nullptr, nullptr);

  // 3) Attention per group: P = exp(q@k^T) w/ partial row-sums; yT = vT@P^T / l.
  for (int g = 0; g < 4; g += group) {
    dim3 gs(16, 16, group);
    gemm256<M_EXPSUM><<<gs, blk2, 0, stream>>>(q + g * SD, 768, SD, k + g * SD, 768, SD,
                                               att, 4096, 16777216L, 768, nullptr, 1.f,
                                               nullptr, lsum2 + g * 65536L);
    dim3 gpv(16, 3, group);
    gemm256<M_DIVL><<<gpv, blk2, 0, stream>>>(vT2 + g * 4096L, 16384, 4096L,
                                              att, 4096, 16777216L,
                                              q + g * SD, 4096, SD, 4096, nullptr, 1.f,
                                              nullptr, lsum2 + g * 65536L);
  }

  // 4) out = y' @ Wc^T + bc  (q region flat == y' [16384][768]); fp32 out per flag.
  dim3 gout(3, 64, 1);
  gemm256<M_PLAIN><<<gout, blk2, 0, stream>>>(q, 768, 0, Wn + 3 * 589824L, 768, 0,
                                              d_out, 768, 0, 768, bn + 2304, 1.f, flg, nullptr);
}